// Round 1
// baseline (11995.615 us; speedup 1.0000x reference)
//
#include <hip/hip_runtime.h>
#include <hip/hip_bf16.h>
#include <stdint.h>

typedef __bf16 bf16;
typedef __bf16 bf16x8 __attribute__((ext_vector_type(8)));
typedef float floatx4 __attribute__((ext_vector_type(4)));

#define T_STEPS 512
#define BATCH   64
#define HID     1024
#define GN      3072      // 3 gates * HID
#define KDIM    1024
#define TB      (T_STEPS*BATCH)   // 32768

__device__ __forceinline__ float sigmoidf_(float x) {
  return 1.0f / (1.0f + __expf(-x));
}

// ---------------- small prep kernels ----------------

__global__ void cvt_f32_to_bf16(const float* __restrict__ src, bf16* __restrict__ dst, int n4) {
  int i = blockIdx.x * blockDim.x + threadIdx.x;
  if (i < n4) {
    float4 v = ((const float4*)src)[i];
    union { bf16 h[4]; uint2 u; } p;
    p.h[0] = (bf16)v.x; p.h[1] = (bf16)v.y; p.h[2] = (bf16)v.z; p.h[3] = (bf16)v.w;
    ((uint2*)dst)[i] = p.u;
  }
}

__global__ void combine_bias(const float* __restrict__ a, const float* __restrict__ b,
                             float* __restrict__ o, int n) {
  int i = blockIdx.x * blockDim.x + threadIdx.x;
  if (i < n) o[i] = a[i] + b[i];
}

__global__ void sigmoid_vec(const float* __restrict__ f, float* __restrict__ o, int n) {
  int i = blockIdx.x * blockDim.x + threadIdx.x;
  if (i < n) o[i] = sigmoidf_(f[i]);
}

__global__ void zero_words(uint32_t* __restrict__ p, int n) {
  int i = blockIdx.x * blockDim.x + threadIdx.x;
  if (i < n) p[i] = 0u;
}

// ---------------- big GEMM: C[M][3072] = A[M][1024] @ W[3072][1024]^T + bias ----------------
// 128x128 tile, 4 waves in 2x2, each wave 64x64 (4x4 MFMA 16x16x32 tiles), K-chunk 64.

__global__ __launch_bounds__(256) void gemm_nt_bias(
    const bf16* __restrict__ A,     // [M][1024] row-major
    const bf16* __restrict__ W,     // [3072][1024] row-major
    const float* __restrict__ bias, // [3072]
    bf16* __restrict__ C)           // [M][3072]
{
  __shared__ __align__(16) bf16 As[128][72];
  __shared__ __align__(16) bf16 Bs[128][72];
  const int tid  = threadIdx.x;
  const int lane = tid & 63;
  const int wave = tid >> 6;
  const int wm = (wave >> 1) * 64;
  const int wn = (wave & 1) * 64;
  const size_t m0 = (size_t)blockIdx.x * 128;
  const size_t n0 = (size_t)blockIdx.y * 128;
  const int fr = lane & 15, fk = (lane >> 4) * 8;

  floatx4 acc[4][4] = {};

  for (int k0 = 0; k0 < KDIM; k0 += 64) {
#pragma unroll
    for (int i = 0; i < 4; ++i) {
      int idx = tid + i * 256;
      int row = idx >> 3, seg = idx & 7;     // 8 x 16B per 64-elem row
      *(uint4*)&As[row][seg * 8] = *(const uint4*)(A + (m0 + row) * KDIM + k0 + seg * 8);
      *(uint4*)&Bs[row][seg * 8] = *(const uint4*)(W + (n0 + row) * KDIM + k0 + seg * 8);
    }
    __syncthreads();
#pragma unroll
    for (int ks = 0; ks < 2; ++ks) {
      bf16x8 af[4], bv[4];
#pragma unroll
      for (int i = 0; i < 4; ++i) af[i] = *(const bf16x8*)&As[wm + i * 16 + fr][ks * 32 + fk];
#pragma unroll
      for (int j = 0; j < 4; ++j) bv[j] = *(const bf16x8*)&Bs[wn + j * 16 + fr][ks * 32 + fk];
#pragma unroll
      for (int i = 0; i < 4; ++i)
#pragma unroll
        for (int j = 0; j < 4; ++j)
          acc[i][j] = __builtin_amdgcn_mfma_f32_16x16x32_bf16(af[i], bv[j], acc[i][j], 0, 0, 0);
    }
    __syncthreads();
  }

  const int col0 = lane & 15, row0 = (lane >> 4) * 4;
#pragma unroll
  for (int j = 0; j < 4; ++j) {
    const size_t n = n0 + wn + j * 16 + col0;
    const float bval = bias[n];
#pragma unroll
    for (int i = 0; i < 4; ++i) {
#pragma unroll
      for (int r = 0; r < 4; ++r) {
        const size_t m = m0 + wm + i * 16 + row0 + r;
        C[m * GN + n] = (bf16)(acc[i][j][r] + bval);
      }
    }
  }
}

// ---------------- recurrent step kernel ----------------
// 64 blocks: block jt owns j in [jt*16, jt*16+16). Computes, for all 64 batch rows,
// the 3 gate preactivation tiles (i/o/z) = h_prev @ R^T restricted to its j-slice,
// then fuses the cell update.

__global__ __launch_bounds__(256) void sublstm_step(
    const bf16* __restrict__ h_prev,  // [64][1024]
    const bf16* __restrict__ R,       // [3072][1024]
    const bf16* __restrict__ Gx_t,    // [64][3072]  x-projection + biases (bf16)
    const float* __restrict__ fg,     // [1024] sigmoid(f)
    float* __restrict__ c_state,      // [64][1024]
    bf16* __restrict__ h_out_b,       // [64][1024]
    float* __restrict__ h_out_f)      // optional [64][1024]
{
  __shared__ __align__(16) bf16 As[64][136];
  __shared__ __align__(16) bf16 Bs[48][136];
  const int tid  = threadIdx.x;
  const int lane = tid & 63;
  const int wave = tid >> 6;          // wave owns batch rows [wave*16, wave*16+16)
  const int jt = blockIdx.x;          // 0..63
  const int fr = lane & 15, fk = (lane >> 4) * 8;

  floatx4 acc0 = {0.f, 0.f, 0.f, 0.f};
  floatx4 acc1 = acc0, acc2 = acc0;

  for (int kc = 0; kc < 8; ++kc) {
    const int k0 = kc * 128;
    // stage A (h_prev): 64 rows x 128 cols -> 1024 16B chunks
#pragma unroll
    for (int i = 0; i < 4; ++i) {
      int idx = tid + i * 256;
      int row = idx >> 4, seg = idx & 15;
      *(uint4*)&As[row][seg * 8] = *(const uint4*)(h_prev + (size_t)row * KDIM + k0 + seg * 8);
    }
    // stage B (R rows for gates i/o/z at this j-tile): 48 rows x 128 cols
#pragma unroll
    for (int i = 0; i < 3; ++i) {
      int idx = tid + i * 256;
      int row = idx >> 4, seg = idx & 15;
      int g = row >> 4, jj = row & 15;
      int n = g * HID + jt * 16 + jj;
      *(uint4*)&Bs[row][seg * 8] = *(const uint4*)(R + (size_t)n * KDIM + k0 + seg * 8);
    }
    __syncthreads();
#pragma unroll
    for (int ks = 0; ks < 4; ++ks) {
      bf16x8 a  = *(const bf16x8*)&As[wave * 16 + fr][ks * 32 + fk];
      bf16x8 b0 = *(const bf16x8*)&Bs[0  + fr][ks * 32 + fk];
      bf16x8 b1 = *(const bf16x8*)&Bs[16 + fr][ks * 32 + fk];
      bf16x8 b2 = *(const bf16x8*)&Bs[32 + fr][ks * 32 + fk];
      acc0 = __builtin_amdgcn_mfma_f32_16x16x32_bf16(a, b0, acc0, 0, 0, 0);
      acc1 = __builtin_amdgcn_mfma_f32_16x16x32_bf16(a, b1, acc1, 0, 0, 0);
      acc2 = __builtin_amdgcn_mfma_f32_16x16x32_bf16(a, b2, acc2, 0, 0, 0);
    }
    __syncthreads();
  }

  // epilogue: C/D layout col=lane&15, row=(lane>>4)*4+r
  const int j = jt * 16 + fr;
  const float fgj = fg[j];
#pragma unroll
  for (int r = 0; r < 4; ++r) {
    const int b = wave * 16 + (lane >> 4) * 4 + r;
    const bf16* gx = Gx_t + (size_t)b * GN;
    float ig = sigmoidf_(acc0[r] + (float)gx[j]);
    float og = sigmoidf_(acc1[r] + (float)gx[HID + j]);
    float zg = sigmoidf_(acc2[r] + (float)gx[2 * HID + j]);
    size_t ci = (size_t)b * HID + j;
    float c = c_state[ci] * fgj + zg - ig;
    c_state[ci] = c;
    float h = sigmoidf_(c) - og;
    h_out_b[ci] = (bf16)h;
    if (h_out_f) h_out_f[ci] = h;
  }
}

// ---------------- finalize: h_final[2][64][1024], c_final[2][64][1024] ----------------

__global__ void finalize_kernel(const bf16* __restrict__ h0_last,
                                const float* __restrict__ out_last,
                                const float* __restrict__ c0,
                                const float* __restrict__ c1,
                                float* __restrict__ dst) {
  int i = blockIdx.x * blockDim.x + threadIdx.x;   // 0..65535
  if (i < BATCH * HID) {
    dst[i]                      = (float)h0_last[i];  // h_final layer 0
    dst[BATCH * HID + i]        = out_last[i];        // h_final layer 1
    dst[2 * BATCH * HID + i]    = c0[i];              // c_final layer 0
    dst[3 * BATCH * HID + i]    = c1[i];              // c_final layer 1
  }
}

// ---------------- launch ----------------

extern "C" void kernel_launch(void* const* d_in, const int* in_sizes, int n_in,
                              void* d_out, int out_size, void* d_ws, size_t ws_size,
                              hipStream_t stream) {
  const float* x   = (const float*)d_in[0];
  const float* W0  = (const float*)d_in[1];
  const float* R0  = (const float*)d_in[2];
  const float* bi0 = (const float*)d_in[3];
  const float* bh0 = (const float*)d_in[4];
  const float* f0  = (const float*)d_in[5];
  const float* W1  = (const float*)d_in[6];
  const float* R1  = (const float*)d_in[7];
  const float* bi1 = (const float*)d_in[8];
  const float* bh1 = (const float*)d_in[9];
  const float* f1  = (const float*)d_in[10];
  float* out = (float*)d_out;

  char* ws = (char*)d_ws;
  size_t off = 0;
  auto alloc = [&](size_t bytes) {
    char* p = ws + off;
    off += (bytes + 255) & ~(size_t)255;
    return p;
  };
  bf16* W0b = (bf16*)alloc((size_t)GN * KDIM * 2);
  bf16* R0b = (bf16*)alloc((size_t)GN * KDIM * 2);
  bf16* W1b = (bf16*)alloc((size_t)GN * KDIM * 2);
  bf16* R1b = (bf16*)alloc((size_t)GN * KDIM * 2);
  bf16* xb  = (bf16*)alloc((size_t)TB * KDIM * 2);
  bf16* h0b = (bf16*)alloc((size_t)TB * HID * 2);
  bf16* Gx  = (bf16*)alloc((size_t)TB * GN * 2);
  float* b0c = (float*)alloc(GN * 4);
  float* b1c = (float*)alloc(GN * 4);
  float* fg0 = (float*)alloc(HID * 4);
  float* fg1 = (float*)alloc(HID * 4);
  // the next three must stay contiguous (zeroed in one kernel)
  float* c0s = (float*)alloc((size_t)BATCH * HID * 4);
  float* c1s = (float*)alloc((size_t)BATCH * HID * 4);
  bf16*  zb  = (bf16*)alloc((size_t)BATCH * HID * 2);
  bf16*  h1p = (bf16*)alloc((size_t)2 * BATCH * HID * 2);

  // --- prep ---
  {
    int n4 = GN * KDIM / 4;
    int blocks = (n4 + 255) / 256;
    cvt_f32_to_bf16<<<blocks, 256, 0, stream>>>(W0, W0b, n4);
    cvt_f32_to_bf16<<<blocks, 256, 0, stream>>>(R0, R0b, n4);
    cvt_f32_to_bf16<<<blocks, 256, 0, stream>>>(W1, W1b, n4);
    cvt_f32_to_bf16<<<blocks, 256, 0, stream>>>(R1, R1b, n4);
  }
  {
    int n4 = TB * KDIM / 4;
    cvt_f32_to_bf16<<<(n4 + 255) / 256, 256, 0, stream>>>(x, xb, n4);
  }
  combine_bias<<<(GN + 255) / 256, 256, 0, stream>>>(bi0, bh0, b0c, GN);
  combine_bias<<<(GN + 255) / 256, 256, 0, stream>>>(bi1, bh1, b1c, GN);
  sigmoid_vec<<<(HID + 255) / 256, 256, 0, stream>>>(f0, fg0, HID);
  sigmoid_vec<<<(HID + 255) / 256, 256, 0, stream>>>(f1, fg1, HID);
  {
    int nwords = (BATCH * HID * 4 * 2 + BATCH * HID * 2) / 4;  // c0s + c1s + zb
    zero_words<<<(nwords + 255) / 256, 256, 0, stream>>>((uint32_t*)c0s, nwords);
  }

  // --- layer 0 ---
  gemm_nt_bias<<<dim3(TB / 128, GN / 128), 256, 0, stream>>>(xb, W0b, b0c, Gx);
  for (int t = 0; t < T_STEPS; ++t) {
    const bf16* h_src = (t == 0) ? zb : (h0b + (size_t)(t - 1) * BATCH * HID);
    sublstm_step<<<64, 256, 0, stream>>>(h_src, R0b,
                                         Gx + (size_t)t * BATCH * GN, fg0, c0s,
                                         h0b + (size_t)t * BATCH * HID, nullptr);
  }

  // --- layer 1 ---
  gemm_nt_bias<<<dim3(TB / 128, GN / 128), 256, 0, stream>>>(h0b, W1b, b1c, Gx);
  for (int t = 0; t < T_STEPS; ++t) {
    const bf16* h_src = (t == 0) ? zb : (h1p + (size_t)((t - 1) & 1) * BATCH * HID);
    sublstm_step<<<64, 256, 0, stream>>>(h_src, R1b,
                                         Gx + (size_t)t * BATCH * GN, fg1, c1s,
                                         h1p + (size_t)(t & 1) * BATCH * HID,
                                         out + (size_t)t * BATCH * HID);
  }

  // --- finals ---
  finalize_kernel<<<(BATCH * HID + 255) / 256, 256, 0, stream>>>(
      h0b + (size_t)(T_STEPS - 1) * BATCH * HID,
      out + (size_t)(T_STEPS - 1) * BATCH * HID,
      c0s, c1s,
      out + (size_t)T_STEPS * BATCH * HID);
}